// Round 11
// baseline (64.981 us; speedup 1.0000x reference)
//
#include <hip/hip_runtime.h>

#define TS 64
#define HD 16
#define SEGLEN 16
#define RAY_EXT 10.0f

typedef float    v4f  __attribute__((ext_vector_type(4)));
typedef _Float16 v8h  __attribute__((ext_vector_type(8)));
typedef unsigned v4u  __attribute__((ext_vector_type(4)));
typedef __fp16   f16x2 __attribute__((ext_vector_type(2)));
typedef __fp16   f16x4 __attribute__((ext_vector_type(4)));
typedef __fp16   f16x8 __attribute__((ext_vector_type(8)));

__device__ __forceinline__ float fast_exp2(float x) { return __builtin_amdgcn_exp2f(x); }
__device__ __forceinline__ float fast_log2(float x) { return __builtin_amdgcn_logf(x); }

// f32 pair -> packed f16x2 (v_cvt_pkrtz_f16_f32), no asm
__device__ __forceinline__ unsigned pk2u(float a, float b) {
    return __builtin_bit_cast(unsigned, __builtin_amdgcn_cvt_pkrtz(a, b));
}

// build an MFMA fragment (k-slots 0..3 live, 4..7 zero) from two packed pairs,
// letting the compiler see the whole dataflow (no asm-opaque movs)
__device__ __forceinline__ v8h frag_pk(f16x2 lo, f16x2 hi) {
    f16x4 a = __builtin_shufflevector(lo, hi, 0, 1, 2, 3);
    f16x4 z = {(__fp16)0.f, (__fp16)0.f, (__fp16)0.f, (__fp16)0.f};
    f16x8 r = __builtin_shufflevector(a, z, 0, 1, 2, 3, 4, 5, 6, 7);
    return __builtin_bit_cast(v8h, r);
}

__device__ __forceinline__ v8h frag_u32(unsigned lo, unsigned hi) {
    return __builtin_bit_cast(v8h, (v4u){lo, hi, 0u, 0u});
}

__device__ __forceinline__ v4f mfma32(v8h a, v8h b, v4f c) {
    return __builtin_amdgcn_mfma_f32_16x16x32_f16(a, b, c, 0, 0, 0);
}

__global__ __launch_bounds__(256) void radiance_kernel(
    const float* __restrict__ rays_o,
    const float* __restrict__ rays_d,
    const float* __restrict__ u,      // (T, N)
    const float* __restrict__ aabb,   // (2,3)
    const float* __restrict__ W1,     // (3,16)
    const float* __restrict__ b1,     // (16)
    const float* __restrict__ Wsigma, // (16,1)
    const float* __restrict__ Wcolor, // (16,3)
    const float* __restrict__ Wdir,   // (3,3)
    float* __restrict__ out,          // (N,5)
    int N)
{
    const float LOG2E = 1.44269504088896340736f;
    const float eps = 1e-9f;

    int tid  = blockIdx.x * blockDim.x + threadIdx.x;
    int lane = threadIdx.x & 63;
    int s    = lane & 15;     // ray-within-wave == MFMA column
    int grp  = lane >> 4;     // segment 0..3     == MFMA k/row block
    int wave = tid >> 6;
    int ray  = wave * 16 + s;

    float ox = rays_o[ray * 3 + 0];
    float oy = rays_o[ray * 3 + 1];
    float oz = rays_o[ray * 3 + 2];
    float dx = rays_d[ray * 3 + 0];
    float dy = rays_d[ray * 3 + 1];
    float dz = rays_d[ray * 3 + 2];

    float a0x = aabb[0], a0y = aabb[1], a0z = aabb[2];
    float a1x = aabb[3], a1y = aabb[4], a1z = aabb[5];

    // slab test (no early return: MFMA needs full waves)
    float dsx = (fabsf(dx) < eps) ? eps : dx;
    float dsy = (fabsf(dy) < eps) ? eps : dy;
    float dsz = (fabsf(dz) < eps) ? eps : dz;
    float t1x = (a0x - ox) / dsx, t2x = (a1x - ox) / dsx;
    float t1y = (a0y - oy) / dsy, t2y = (a1y - oy) / dsy;
    float t1z = (a0z - oz) / dsz, t2z = (a1z - oz) / dsz;
    float tnear = fmaxf(fmaxf(fminf(t1x, t2x), fmaxf(fminf(t1y, t2y), fminf(t1z, t2z))), 0.0f);
    float tfar  = fminf(fmaxf(t1x, t2x), fminf(fmaxf(t1y, t2y), fmaxf(t1z, t2z)));
    bool active = tnear < tfar;
    // sanitize inactive rays: pipeline stays finite, all weights w == 0.
    if (!active) { tnear = 0.0f; tfar = 0.0f; }

    // ---- A1: A1[m=s][slot i] = {W1[0][s], W1[1][s], W1[2][s], b1[s]}
    unsigned w1lo = pk2u(W1[0 * HD + s], W1[1 * HD + s]);
    unsigned w1hi = pk2u(W1[2 * HD + s], b1[s]);

    // ---- A2: row m = s -> output o = s&3, owner pass = s>>2.
    //      A2[m=s][slot i] = W2eff[o][4*grp + i], pre-scaled into exp2 domain.
    int oidx = s & 3;
    int rgrp = s >> 2;
    float w2v0, w2v1, w2v2, w2v3;
    {
        int k0 = 4 * grp;
        if (oidx == 0) {
            w2v0 = LOG2E * Wsigma[k0 + 0]; w2v1 = LOG2E * Wsigma[k0 + 1];
            w2v2 = LOG2E * Wsigma[k0 + 2]; w2v3 = LOG2E * Wsigma[k0 + 3];
        } else {
            int c = oidx - 1;
            w2v0 = -LOG2E * Wcolor[(k0 + 0) * 3 + c];
            w2v1 = -LOG2E * Wcolor[(k0 + 1) * 3 + c];
            w2v2 = -LOG2E * Wcolor[(k0 + 2) * 3 + c];
            w2v3 = -LOG2E * Wcolor[(k0 + 3) * 3 + c];
        }
    }
    unsigned a2lo = pk2u(w2v0, w2v1);
    unsigned a2hi = pk2u(w2v2, w2v3);

    // hoisted per-pass masked fragments (lane-constant, static indices)
    v8h a1f0 = frag_u32(grp == 0 ? w1lo : 0u, grp == 0 ? w1hi : 0u);
    v8h a1f1 = frag_u32(grp == 1 ? w1lo : 0u, grp == 1 ? w1hi : 0u);
    v8h a1f2 = frag_u32(grp == 2 ? w1lo : 0u, grp == 2 ? w1hi : 0u);
    v8h a1f3 = frag_u32(grp == 3 ? w1lo : 0u, grp == 3 ? w1hi : 0u);
    v8h a2f0 = frag_u32(rgrp == 0 ? a2lo : 0u, rgrp == 0 ? a2hi : 0u);
    v8h a2f1 = frag_u32(rgrp == 1 ? a2lo : 0u, rgrp == 1 ? a2hi : 0u);
    v8h a2f2 = frag_u32(rgrp == 2 ? a2lo : 0u, rgrp == 2 ? a2hi : 0u);
    v8h a2f3 = frag_u32(rgrp == 3 ? a2lo : 0u, rgrp == 3 ? a2hi : 0u);
    const v4f zero4 = {0.f, 0.f, 0.f, 0.f};

    // direction encoding (pre-scaled by -log2e), per-ray
    float dn = sqrtf(dx * dx + dy * dy + dz * dz);
    float inv_dn = 1.0f / dn;
    float ux = dx * inv_dn, uy = dy * inv_dn, uz = dz * inv_dn;
    float dd0 = -LOG2E * (ux * Wdir[0] + uy * Wdir[3] + uz * Wdir[6]);
    float dd1 = -LOG2E * (ux * Wdir[1] + uy * Wdir[4] + uz * Wdir[7]);
    float dd2 = -LOG2E * (ux * Wdir[2] + uy * Wdir[5] + uz * Wdir[8]);

    const float invT = 1.0f / (float)TS;
    float rngT = (tfar - tnear) * invT;
    float tfinal = tfar * RAY_EXT;

    const int t0 = grp * SEGLEN;
    float t0f = (float)t0;

    float cm0 = 0.f, cm1 = 0.f, cm2 = 0.f, am = 0.f, dm = 0.f;
    float Tr = 1.0f;

    // rolling u prefetch, 32-bit offsets (max index 64*262144 < 2^31)
    int uoff  = t0 * N + ray;
    int ulim  = (TS - 1) * N + ray;
    float u_cur = u[uoff];
    float u_nxt = u[uoff + N];
    int upre = uoff + 2 * N;
    if (upre > ulim) upre = ulim;

    float ts  = fmaf(rngT, t0f + u_cur, tnear);
    float tf1 = t0f + 1.0f;

    // one volumetric step: MLP via MFMA + pointwise composite
    auto doStep = [&](float delta, float tsv) {
        float x = fmaf(tsv, dx, ox);
        float y = fmaf(tsv, dy, oy);
        float z = fmaf(tsv, dz, oz);
        v8h bin = frag_pk(__builtin_amdgcn_cvt_pkrtz(x, y),
                          __builtin_amdgcn_cvt_pkrtz(z, 1.0f));

        // layer 1: 4 independent MFMAs (shared B)
        v4f d0 = mfma32(a1f0, bin, zero4);
        v4f d1 = mfma32(a1f1, bin, zero4);
        v4f d2 = mfma32(a1f2, bin, zero4);
        v4f d3 = mfma32(a1f3, bin, zero4);

        // relu in f32, pack via native pkrtz (R9 numeric path)
        v8h h0 = frag_pk(__builtin_amdgcn_cvt_pkrtz(fmaxf(d0[0], 0.f), fmaxf(d0[1], 0.f)),
                         __builtin_amdgcn_cvt_pkrtz(fmaxf(d0[2], 0.f), fmaxf(d0[3], 0.f)));
        v8h h1 = frag_pk(__builtin_amdgcn_cvt_pkrtz(fmaxf(d1[0], 0.f), fmaxf(d1[1], 0.f)),
                         __builtin_amdgcn_cvt_pkrtz(fmaxf(d1[2], 0.f), fmaxf(d1[3], 0.f)));
        v8h h2 = frag_pk(__builtin_amdgcn_cvt_pkrtz(fmaxf(d2[0], 0.f), fmaxf(d2[1], 0.f)),
                         __builtin_amdgcn_cvt_pkrtz(fmaxf(d2[2], 0.f), fmaxf(d2[3], 0.f)));
        v8h h3 = frag_pk(__builtin_amdgcn_cvt_pkrtz(fmaxf(d3[0], 0.f), fmaxf(d3[1], 0.f)),
                         __builtin_amdgcn_cvt_pkrtz(fmaxf(d3[2], 0.f), fmaxf(d3[3], 0.f)));

        // layer 2: serial C-chain (R9 summation order)
        v4f acc = mfma32(a2f0, h0, zero4);
        acc = mfma32(a2f1, h1, acc);
        acc = mfma32(a2f2, h2, acc);
        acc = mfma32(a2f3, h3, acc);

        float sp = acc[0];
        float c0 = acc[1] + dd0;
        float c1 = acc[2] + dd1;
        float c2 = acc[3] + dd2;

        float F = fmaxf(sp, 0.0f) + fast_log2(1.0f + fast_exp2(-fabsf(sp)));
        float e = fast_exp2(-F * (delta * dn));

        float col0 = __builtin_amdgcn_rcpf(1.0f + fast_exp2(c0));
        float col1 = __builtin_amdgcn_rcpf(1.0f + fast_exp2(c1));
        float col2 = __builtin_amdgcn_rcpf(1.0f + fast_exp2(c2));

        float w = (1.0f - e) * Tr;
        Tr *= e;

        cm0 = fmaf(w, col0, cm0);
        cm1 = fmaf(w, col1, cm1);
        cm2 = fmaf(w, col2, cm2);
        am += w;
        dm = fmaf(w, tsv, dm);
    };

#pragma unroll 5
    for (int t = 0; t < SEGLEN - 1; ++t) {
        float u_fut = u[upre];
        upre += N; if (upre > ulim) upre = ulim;

        float tsn = fmaf(rngT, tf1 + u_nxt, tnear);
        doStep(tsn - ts, ts);

        ts = tsn;
        u_nxt = u_fut;
        tf1 += 1.0f;
    }
    { // peeled last step (t = SEGLEN-1): tend select is per-lane only
        float tsn = fmaf(rngT, tf1 + u_nxt, tnear);
        float tend = (grp == 3) ? tfinal : tsn;
        doStep(tend - ts, ts);
    }

    // ---- combine 4 segments across lane groups: butterfly xor 16, then 32.
#pragma unroll
    for (int x = 16; x <= 32; x <<= 1) {
        float pcm0 = __shfl_xor(cm0, x, 64);
        float pcm1 = __shfl_xor(cm1, x, 64);
        float pcm2 = __shfl_xor(cm2, x, 64);
        float pam  = __shfl_xor(am, x, 64);
        float pdm  = __shfl_xor(dm, x, 64);
        float pTr  = __shfl_xor(Tr, x, 64);
        cm0 = fmaf(Tr, pcm0, cm0);
        cm1 = fmaf(Tr, pcm1, cm1);
        cm2 = fmaf(Tr, pcm2, cm2);
        am  = fmaf(Tr, pam,  am);
        dm  = fmaf(Tr, pdm,  dm);
        Tr *= pTr;
    }

    if (grp == 0) {
        float* o5 = out + (size_t)ray * 5;
        o5[0] = active ? cm0 : 0.0f;
        o5[1] = active ? cm1 : 0.0f;
        o5[2] = active ? cm2 : 0.0f;
        o5[3] = active ? am  : 0.0f;
        o5[4] = active ? dm  : 0.0f;
    }
}

extern "C" void kernel_launch(void* const* d_in, const int* in_sizes, int n_in,
                              void* d_out, int out_size, void* d_ws, size_t ws_size,
                              hipStream_t stream) {
    const float* rays_o = (const float*)d_in[0];
    const float* rays_d = (const float*)d_in[1];
    const float* u      = (const float*)d_in[2];
    const float* aabb   = (const float*)d_in[3];
    const float* W1     = (const float*)d_in[4];
    const float* b1     = (const float*)d_in[5];
    const float* Wsigma = (const float*)d_in[6];
    const float* Wcolor = (const float*)d_in[7];
    const float* Wdir   = (const float*)d_in[8];
    float* out = (float*)d_out;

    int N = in_sizes[0] / 3;
    long long threads = (long long)N * 4;   // 4 lanes (segments) per ray
    int blocks = (int)((threads + 255) / 256);
    radiance_kernel<<<blocks, 256, 0, stream>>>(rays_o, rays_d, u, aabb,
                                                W1, b1, Wsigma, Wcolor, Wdir,
                                                out, N);
}